// Round 4
// baseline (331.819 us; speedup 1.0000x reference)
//
#include <hip/hip_runtime.h>
#include <hip/hip_bf16.h>

// ---------------------------------------------------------------------------
// Fused attention: x@Wqkv -> q,k,v ; flash split-KV attention over
// concat(past_k, k_new) ; combine ; @Wproj -> out.
// B=2, N=256, DIM=1024, H=16, D=64, L=8192, total keys 8448 = 132 x 64.
// R3b: NSPLIT=32 (4 blocks/CU), double-buffered LDS (1 barrier/step),
// v_cvt_pk_bf16_f32 for all f32->bf16, exp2-domain softmax
// (__builtin_amdgcn_exp2f; __exp2f collides with glibc math.h).
// ---------------------------------------------------------------------------

#define BB 2
#define NH 16
#define NQ 256
#define HD 64
#define DIMC 1024
#define LPAST 8192
#define TOTK 8448
#define NSPLIT 32
// 132 steps of 64 keys: splits 0..3 take 5 steps, 4..31 take 4.
// Split 31 covers steps 128..131 == exactly the k_new/v_new region.

typedef __attribute__((ext_vector_type(8))) short short8;
typedef __attribute__((ext_vector_type(4))) float f32x4;
typedef __attribute__((ext_vector_type(4))) int int4v;

#define DEVI static __device__ __forceinline__

DEVI float exp2g(float x) { return __builtin_amdgcn_exp2f(x); }  // v_exp_f32

DEVI int cvtpk(float lo, float hi) {     // dword = {bf16(lo), bf16(hi)}
  int r;
  asm("v_cvt_pk_bf16_f32 %0, %1, %2" : "=v"(r) : "v"(lo), "v"(hi));
  return r;
}
DEVI short f2bf(float f) {               // scalar f32 -> bf16 (RNE)
  union { float f; unsigned u; } v; v.f = f;
  unsigned r = v.u + 0x7FFFu + ((v.u >> 16) & 1u);
  return (short)(r >> 16);
}

// ---------------------------------------------------------------------------
// Generic 64x64-tile bf16 MFMA GEMM, f32 inputs converted during staging.
// MODE 0: Cout[row*Nn+col] = acc + bias[col]
// MODE 1: scatter into q (bf16, *0.125*log2e), k_new, v_new  [B,H,N,D]
// ---------------------------------------------------------------------------
template<int MODE>
__global__ __launch_bounds__(256, 2) void gemm_k(
    const float* __restrict__ A, const float* __restrict__ Bm,
    const float* __restrict__ bias, float* __restrict__ Cout,
    short* __restrict__ qbuf, float* __restrict__ knew, float* __restrict__ vnew,
    int M, int Nn, int K)
{
  __shared__ alignas(16) short As[64][72];   // [m][k] bf16, +8 pad
  __shared__ alignas(16) short Bs[64][72];   // [n][k] bf16 (B transposed)
  const int tid = threadIdx.x;
  const int lane = tid & 63, wave = tid >> 6;
  const int nblk = Nn >> 6;
  const int bi = blockIdx.x / nblk, bj = blockIdx.x % nblk;
  const int wm = wave >> 1, wn = wave & 1;
  const int g = lane >> 4, l16 = lane & 15;
  f32x4 acc[2][2] = {};
  const int r = tid >> 2, q4 = (tid & 3) << 4;

  for (int k0 = 0; k0 < K; k0 += 64) {
    const float* pa = A + (size_t)(bi * 64 + r) * K + (k0 + q4);
    float4 a0 = ((const float4*)pa)[0];
    float4 a1 = ((const float4*)pa)[1];
    float4 a2 = ((const float4*)pa)[2];
    float4 a3 = ((const float4*)pa)[3];
    const float* pb = Bm + (size_t)(k0 + r) * Nn + (bj * 64 + q4);
    float4 b0 = ((const float4*)pb)[0];
    float4 b1 = ((const float4*)pb)[1];
    float4 b2 = ((const float4*)pb)[2];
    float4 b3 = ((const float4*)pb)[3];
    __syncthreads();
    {
      int4v p0 = {cvtpk(a0.x,a0.y), cvtpk(a0.z,a0.w), cvtpk(a1.x,a1.y), cvtpk(a1.z,a1.w)};
      int4v p1 = {cvtpk(a2.x,a2.y), cvtpk(a2.z,a2.w), cvtpk(a3.x,a3.y), cvtpk(a3.z,a3.w)};
      *(int4v*)&As[r][q4]     = p0;
      *(int4v*)&As[r][q4 + 8] = p1;
    }
    Bs[q4+ 0][r] = f2bf(b0.x); Bs[q4+ 1][r] = f2bf(b0.y);
    Bs[q4+ 2][r] = f2bf(b0.z); Bs[q4+ 3][r] = f2bf(b0.w);
    Bs[q4+ 4][r] = f2bf(b1.x); Bs[q4+ 5][r] = f2bf(b1.y);
    Bs[q4+ 6][r] = f2bf(b1.z); Bs[q4+ 7][r] = f2bf(b1.w);
    Bs[q4+ 8][r] = f2bf(b2.x); Bs[q4+ 9][r] = f2bf(b2.y);
    Bs[q4+10][r] = f2bf(b2.z); Bs[q4+11][r] = f2bf(b2.w);
    Bs[q4+12][r] = f2bf(b3.x); Bs[q4+13][r] = f2bf(b3.y);
    Bs[q4+14][r] = f2bf(b3.z); Bs[q4+15][r] = f2bf(b3.w);
    __syncthreads();
    #pragma unroll
    for (int kf = 0; kf < 2; ++kf) {
      short8 af[2], bfv[2];
      #pragma unroll
      for (int mt = 0; mt < 2; ++mt)
        af[mt] = *(const short8*)&As[wm*32 + mt*16 + l16][kf*32 + g*8];
      #pragma unroll
      for (int nt = 0; nt < 2; ++nt)
        bfv[nt] = *(const short8*)&Bs[wn*32 + nt*16 + l16][kf*32 + g*8];
      #pragma unroll
      for (int mt = 0; mt < 2; ++mt)
        #pragma unroll
        for (int nt = 0; nt < 2; ++nt)
          acc[mt][nt] = __builtin_amdgcn_mfma_f32_16x16x32_bf16(
              af[mt], bfv[nt], acc[mt][nt], 0, 0, 0);
    }
  }

  #pragma unroll
  for (int mt = 0; mt < 2; ++mt)
    #pragma unroll
    for (int nt = 0; nt < 2; ++nt)
      #pragma unroll
      for (int rg = 0; rg < 4; ++rg) {
        int row = bi*64 + wm*32 + mt*16 + g*4 + rg;
        int col = bj*64 + wn*32 + nt*16 + l16;
        float val = acc[mt][nt][rg] + bias[col];
        if (MODE == 0) {
          Cout[(size_t)row * Nn + col] = val;
        } else {
          int which = col >> 10, cc = col & 1023;
          int h = cc >> 6, d = cc & 63;
          int b = row >> 8, n = row & 255;
          size_t idx = (((size_t)(b*NH + h))*NQ + n)*HD + d;
          if (which == 0)      qbuf[idx] = f2bf(val * 0.180336878f); // 0.125*log2(e)
          else if (which == 1) knew[idx] = val;
          else                 vnew[idx] = val;
        }
      }
}

// ---------------------------------------------------------------------------
// Flash attention, split-KV, swapped-QK in-register softmax (exp2 domain).
// Grid: (B*H)*NSPLIT blocks, 256 threads = 4 waves x 64 queries.
// Double-buffered K/V LDS, 1 barrier per 64-key step.
// P lands directly in PV A-fragment layout via key permutation
//   sigma(g,j,kk) = 32kk + 16*(j>>2) + 4g + (j&3),
// matched on the B side by reading Vt[d][sigma] (transposed V in LDS).
// ---------------------------------------------------------------------------
__global__ __launch_bounds__(256, 4) void attn_k(
    const short* __restrict__ qbuf, const float* __restrict__ pastk,
    const float* __restrict__ pastv, const float* __restrict__ knew,
    const float* __restrict__ vnew, float* __restrict__ opart,
    float* __restrict__ mbuf, float* __restrict__ lbuf)
{
  __shared__ alignas(16) short Kt[2][64][72];   // [buf][key][d]
  __shared__ alignas(16) short Vt[2][64][70];   // [buf][d][key], 35-dword stride
  const int tid = threadIdx.x;
  const int lane = tid & 63, wave = tid >> 6;
  const int g = lane >> 4, l16 = lane & 15;
  const int s = blockIdx.x & (NSPLIT - 1), bh = blockIdx.x / NSPLIT;
  const int r = tid >> 2, q4 = (tid & 3) << 4;     // K staging: 1 key x 16 d
  const int kp = tid >> 3, d8 = (tid & 7) << 3;    // V staging: keys 2kp,2kp+1 x 8 d

  // Q fragments (B-operand of S^T): lane holds Q[q=qt*16+l16][d=half*32+g*8..+7]
  short8 qf[4][2];
  #pragma unroll
  for (int qt = 0; qt < 4; ++qt)
    #pragma unroll
    for (int half = 0; half < 2; ++half)
      qf[qt][half] = *(const short8*)(qbuf +
          ((size_t)bh*NQ + wave*64 + qt*16 + l16)*HD + half*32 + g*8);

  f32x4 acc[4][4] = {};     // acc[qt][dt]: q = qt*16+g*4+rg, d = dt*16+l16
  float m_s[4], l_s[4];
  #pragma unroll
  for (int qt = 0; qt < 4; ++qt) { m_s[qt] = -INFINITY; l_s[qt] = 0.f; }

  const int first  = 4*s + (s < 4 ? s : 4);
  const int nsteps = 4 + (s < 4 ? 1 : 0);
  // split 31 is exactly the new-KV region; others are entirely past-KV
  const float* kb = (s == 31) ? knew + ((long long)bh*NQ - LPAST)*HD
                              : pastk + (size_t)bh*LPAST*HD;
  const float* vb = (s == 31) ? vnew + ((long long)bh*NQ - LPAST)*HD
                              : pastv + (size_t)bh*LPAST*HD;

  float4 ka[4], va[2], vc[2];
  auto load = [&](int step) {
    const float* krow = kb + ((size_t)step*64 + r)*HD + q4;
    ka[0] = ((const float4*)krow)[0];
    ka[1] = ((const float4*)krow)[1];
    ka[2] = ((const float4*)krow)[2];
    ka[3] = ((const float4*)krow)[3];
    const float* vrow = vb + ((size_t)step*64 + 2*kp)*HD + d8;
    va[0] = ((const float4*)vrow)[0];
    va[1] = ((const float4*)vrow)[1];
    vc[0] = ((const float4*)(vrow + HD))[0];
    vc[1] = ((const float4*)(vrow + HD))[1];
  };
  auto stage = [&](int b) {
    const float* kf32 = (const float*)ka;
    int4v p0 = {cvtpk(kf32[0],kf32[1]), cvtpk(kf32[2],kf32[3]),
                cvtpk(kf32[4],kf32[5]), cvtpk(kf32[6],kf32[7])};
    int4v p1 = {cvtpk(kf32[8],kf32[9]), cvtpk(kf32[10],kf32[11]),
                cvtpk(kf32[12],kf32[13]), cvtpk(kf32[14],kf32[15])};
    *(int4v*)&Kt[b][r][q4]     = p0;
    *(int4v*)&Kt[b][r][q4 + 8] = p1;
    const float* af = (const float*)va;
    const float* cf = (const float*)vc;
    #pragma unroll
    for (int j = 0; j < 8; ++j)
      *(int*)&Vt[b][d8 + j][2*kp] = cvtpk(af[j], cf[j]);  // lo=key 2kp, hi=2kp+1
  };

  load(first);
  stage(0);
  if (nsteps > 1) load(first + 1);
  __syncthreads();

  for (int it = 0; it < nsteps; ++it) {
    const int cur = it & 1;

    // K fragments (A-operand of S^T): row = key = kt*16+l16, d = half*32+g*8
    short8 kf[4][2];
    #pragma unroll
    for (int kt = 0; kt < 4; ++kt)
      #pragma unroll
      for (int half = 0; half < 2; ++half)
        kf[kt][half] = *(const short8*)&Kt[cur][kt*16 + l16][half*32 + g*8];

    short8 pa[4][2];
    #pragma unroll
    for (int qt = 0; qt < 4; ++qt) {
      f32x4 sv[4];
      #pragma unroll
      for (int kt = 0; kt < 4; ++kt) {
        f32x4 z = {0.f, 0.f, 0.f, 0.f};
        z = __builtin_amdgcn_mfma_f32_16x16x32_bf16(kf[kt][0], qf[qt][0], z, 0,0,0);
        sv[kt] = __builtin_amdgcn_mfma_f32_16x16x32_bf16(kf[kt][1], qf[qt][1], z, 0,0,0);
      }
      float mx = sv[0][0];
      #pragma unroll
      for (int kt = 0; kt < 4; ++kt)
        #pragma unroll
        for (int rg = 0; rg < 4; ++rg) mx = fmaxf(mx, sv[kt][rg]);
      mx = fmaxf(mx, __shfl_xor(mx, 16));
      mx = fmaxf(mx, __shfl_xor(mx, 32));
      float m_new = fmaxf(m_s[qt], mx);
      float al = exp2g(m_s[qt] - m_new);
      float ss = 0.f;
      #pragma unroll
      for (int kt = 0; kt < 4; ++kt)
        #pragma unroll
        for (int rg = 0; rg < 4; ++rg) {
          float p = exp2g(sv[kt][rg] - m_new);
          sv[kt][rg] = p; ss += p;
        }
      ss += __shfl_xor(ss, 16);
      ss += __shfl_xor(ss, 32);
      l_s[qt] = l_s[qt]*al + ss;
      m_s[qt] = m_new;
      #pragma unroll
      for (int rg = 0; rg < 4; ++rg) {
        float a = __shfl(al, g*4 + rg);
        #pragma unroll
        for (int dt = 0; dt < 4; ++dt) acc[qt][dt][rg] *= a;
      }
      int4v w0 = {cvtpk(sv[0][0],sv[0][1]), cvtpk(sv[0][2],sv[0][3]),
                  cvtpk(sv[1][0],sv[1][1]), cvtpk(sv[1][2],sv[1][3])};
      int4v w1 = {cvtpk(sv[2][0],sv[2][1]), cvtpk(sv[2][2],sv[2][3]),
                  cvtpk(sv[3][0],sv[3][1]), cvtpk(sv[3][2],sv[3][3])};
      pa[qt][0] = __builtin_bit_cast(short8, w0);
      pa[qt][1] = __builtin_bit_cast(short8, w1);
    }

    // PV: B-frag slot j <- Vt[d][32kk + 16*(j>>2) + 4g + (j&3)]
    #pragma unroll
    for (int kk = 0; kk < 2; ++kk) {
      short8 vf[4];
      #pragma unroll
      for (int dt = 0; dt < 4; ++dt) {
        const short* vrow = &Vt[cur][dt*16 + l16][kk*32 + 4*g];
        int i0 = *(const int*)(vrow);
        int i1 = *(const int*)(vrow + 2);
        int i2 = *(const int*)(vrow + 16);
        int i3 = *(const int*)(vrow + 18);
        int4v iv = {i0, i1, i2, i3};
        vf[dt] = __builtin_bit_cast(short8, iv);
      }
      #pragma unroll
      for (int qt = 0; qt < 4; ++qt)
        #pragma unroll
        for (int dt = 0; dt < 4; ++dt)
          acc[qt][dt] = __builtin_amdgcn_mfma_f32_16x16x32_bf16(
              pa[qt][kk], vf[dt], acc[qt][dt], 0,0,0);
    }

    if (it + 1 < nsteps) {
      stage(1 - cur);                       // write NEXT step's tile (other buffer)
      if (it + 2 < nsteps) load(first + it + 2);
      __syncthreads();
    }
  }

  // Write partials
  size_t pbase = ((size_t)(bh * NSPLIT + s)) * NQ;
  #pragma unroll
  for (int qt = 0; qt < 4; ++qt)
    #pragma unroll
    for (int dt = 0; dt < 4; ++dt)
      #pragma unroll
      for (int rg = 0; rg < 4; ++rg) {
        int row = wave*64 + qt*16 + g*4 + rg;
        int col = dt*16 + l16;
        opart[(pbase + row)*HD + col] = acc[qt][dt][rg];
      }
  if (g == 0) {
    #pragma unroll
    for (int qt = 0; qt < 4; ++qt) {
      int q = wave*64 + qt*16 + l16;
      mbuf[pbase + q] = m_s[qt];
      lbuf[pbase + q] = l_s[qt];
    }
  }
}

// ---------------------------------------------------------------------------
// Combine NSPLIT partials per (b,h,n); write attn output [B,N,DIM] f32
// ---------------------------------------------------------------------------
__global__ __launch_bounds__(256) void combine_k(
    const float* __restrict__ opart, const float* __restrict__ mbuf,
    const float* __restrict__ lbuf, float* __restrict__ attnout)
{
  const int lane = threadIdx.x & 63, wave = threadIdx.x >> 6;
  const int rid = blockIdx.x * 4 + wave;   // 0 .. B*H*N-1
  const int bh = rid >> 8, n = rid & 255;
  const int b = bh >> 4, h = bh & 15;
  float M = -INFINITY;
  float ms[NSPLIT], ls[NSPLIT];
  #pragma unroll
  for (int s = 0; s < NSPLIT; ++s) {
    size_t base = ((size_t)(bh * NSPLIT + s)) * NQ + n;
    ms[s] = mbuf[base]; ls[s] = lbuf[base];
    M = fmaxf(M, ms[s]);
  }
  float denom = 0.f, o = 0.f;
  #pragma unroll
  for (int s = 0; s < NSPLIT; ++s) {
    float w = exp2g(ms[s] - M);
    denom += w * ls[s];
    o += w * opart[(((size_t)(bh * NSPLIT + s)) * NQ + n) * HD + lane];
  }
  attnout[((size_t)(b * NQ + n)) * DIMC + h * HD + lane] = o / denom;
}

// ---------------------------------------------------------------------------
extern "C" void kernel_launch(void* const* d_in, const int* in_sizes, int n_in,
                              void* d_out, int out_size, void* d_ws, size_t ws_size,
                              hipStream_t stream)
{
  const float* x     = (const float*)d_in[0];
  const float* pastk = (const float*)d_in[1];
  const float* pastv = (const float*)d_in[2];
  const float* wqkv  = (const float*)d_in[3];
  const float* bqkv  = (const float*)d_in[4];
  const float* wproj = (const float*)d_in[5];
  const float* bproj = (const float*)d_in[6];
  float* out = (float*)d_out;
  char* ws = (char*)d_ws;

  size_t off = 0;
  short* qbuf   = (short*)(ws + off); off += (size_t)BB*NH*NQ*HD*2;          // 1MB
  float* knew   = (float*)(ws + off); off += (size_t)BB*NH*NQ*HD*4;          // 2MB
  float* vnew   = (float*)(ws + off); off += (size_t)BB*NH*NQ*HD*4;          // 2MB
  float* opart  = (float*)(ws + off); off += (size_t)BB*NH*NSPLIT*NQ*HD*4;   // 64MB
  float* mbuf   = (float*)(ws + off); off += (size_t)BB*NH*NSPLIT*NQ*4;      // 1MB
  float* lbuf   = (float*)(ws + off); off += (size_t)BB*NH*NSPLIT*NQ*4;      // 1MB
  float* attnout= (float*)(ws + off); off += (size_t)BB*NQ*DIMC*4;           // 2MB

  // 1) QKV projection: [512,1024] x [1024,3072]
  gemm_k<1><<<(512/64)*(3072/64), 256, 0, stream>>>(
      x, wqkv, bqkv, nullptr, qbuf, knew, vnew, 512, 3072, 1024);
  // 2) split-KV flash attention
  attn_k<<<BB*NH*NSPLIT, 256, 0, stream>>>(
      qbuf, pastk, pastv, knew, vnew, opart, mbuf, lbuf);
  // 3) combine partials
  combine_k<<<BB*NH*NQ/4, 256, 0, stream>>>(opart, mbuf, lbuf, attnout);
  // 4) output projection: [512,1024] x [1024,1024]
  gemm_k<0><<<(512/64)*(1024/64), 256, 0, stream>>>(
      attnout, wproj, bproj, out, nullptr, nullptr, nullptr, 512, 1024, 1024);
}

// Round 5
// 113.495 us; speedup vs baseline: 2.9236x; 2.9236x over previous
//
#include <hip/hip_runtime.h>
#include <hip/hip_bf16.h>

// ---------------------------------------------------------------------------
// Fused attention: x@Wqkv -> q,k,v ; flash split-KV attention over
// concat(past_k, k_new) ; combine ; @Wproj -> out.
// B=2, N=256, DIM=1024, H=16, D=64, L=8192, total keys 8448 = 132 x 64.
// R5: 512-thread / 8-wave attn blocks, 32 queries per wave (acc[2][4] = 32
// regs) so the whole wave state fits the 128-VGPR cap of launch_bounds(512,4)
// -> 16 waves/CU without spill. Double-buffered LDS, 1 barrier/step,
// v_cvt_pk_bf16_f32 staging, exp2-domain softmax, sigma-permuted PV.
// ---------------------------------------------------------------------------

#define BB 2
#define NH 16
#define NQ 256
#define HD 64
#define DIMC 1024
#define LPAST 8192
#define TOTK 8448
#define NSPLIT 16
// 132 steps of 64 keys: splits 0..3 take 9 steps, 4..15 take 8.
// Steps 128..131 (inside split 15) read knew/vnew; selected per step.

typedef __attribute__((ext_vector_type(8))) short short8;
typedef __attribute__((ext_vector_type(4))) float f32x4;
typedef __attribute__((ext_vector_type(4))) int int4v;

#define DEVI static __device__ __forceinline__

DEVI float exp2g(float x) { return __builtin_amdgcn_exp2f(x); }  // v_exp_f32

DEVI int cvtpk(float lo, float hi) {     // dword = {bf16(lo), bf16(hi)}
  int r;
  asm("v_cvt_pk_bf16_f32 %0, %1, %2" : "=v"(r) : "v"(lo), "v"(hi));
  return r;
}
DEVI short f2bf(float f) {               // scalar f32 -> bf16 (RNE)
  union { float f; unsigned u; } v; v.f = f;
  unsigned r = v.u + 0x7FFFu + ((v.u >> 16) & 1u);
  return (short)(r >> 16);
}

// ---------------------------------------------------------------------------
// Generic 64x64-tile bf16 MFMA GEMM, f32 inputs converted during staging.
// MODE 0: Cout[row*Nn+col] = acc + bias[col]
// MODE 1: scatter into q (bf16, *0.125*log2e), k_new, v_new  [B,H,N,D]
// ---------------------------------------------------------------------------
template<int MODE>
__global__ __launch_bounds__(256, 2) void gemm_k(
    const float* __restrict__ A, const float* __restrict__ Bm,
    const float* __restrict__ bias, float* __restrict__ Cout,
    short* __restrict__ qbuf, float* __restrict__ knew, float* __restrict__ vnew,
    int M, int Nn, int K)
{
  __shared__ alignas(16) short As[64][72];   // [m][k] bf16, +8 pad
  __shared__ alignas(16) short Bs[64][72];   // [n][k] bf16 (B transposed)
  const int tid = threadIdx.x;
  const int lane = tid & 63, wave = tid >> 6;
  const int nblk = Nn >> 6;
  const int bi = blockIdx.x / nblk, bj = blockIdx.x % nblk;
  const int wm = wave >> 1, wn = wave & 1;
  const int g = lane >> 4, l16 = lane & 15;
  f32x4 acc[2][2] = {};
  const int r = tid >> 2, q4 = (tid & 3) << 4;

  for (int k0 = 0; k0 < K; k0 += 64) {
    const float* pa = A + (size_t)(bi * 64 + r) * K + (k0 + q4);
    float4 a0 = ((const float4*)pa)[0];
    float4 a1 = ((const float4*)pa)[1];
    float4 a2 = ((const float4*)pa)[2];
    float4 a3 = ((const float4*)pa)[3];
    const float* pb = Bm + (size_t)(k0 + r) * Nn + (bj * 64 + q4);
    float4 b0 = ((const float4*)pb)[0];
    float4 b1 = ((const float4*)pb)[1];
    float4 b2 = ((const float4*)pb)[2];
    float4 b3 = ((const float4*)pb)[3];
    __syncthreads();
    {
      int4v p0 = {cvtpk(a0.x,a0.y), cvtpk(a0.z,a0.w), cvtpk(a1.x,a1.y), cvtpk(a1.z,a1.w)};
      int4v p1 = {cvtpk(a2.x,a2.y), cvtpk(a2.z,a2.w), cvtpk(a3.x,a3.y), cvtpk(a3.z,a3.w)};
      *(int4v*)&As[r][q4]     = p0;
      *(int4v*)&As[r][q4 + 8] = p1;
    }
    Bs[q4+ 0][r] = f2bf(b0.x); Bs[q4+ 1][r] = f2bf(b0.y);
    Bs[q4+ 2][r] = f2bf(b0.z); Bs[q4+ 3][r] = f2bf(b0.w);
    Bs[q4+ 4][r] = f2bf(b1.x); Bs[q4+ 5][r] = f2bf(b1.y);
    Bs[q4+ 6][r] = f2bf(b1.z); Bs[q4+ 7][r] = f2bf(b1.w);
    Bs[q4+ 8][r] = f2bf(b2.x); Bs[q4+ 9][r] = f2bf(b2.y);
    Bs[q4+10][r] = f2bf(b2.z); Bs[q4+11][r] = f2bf(b2.w);
    Bs[q4+12][r] = f2bf(b3.x); Bs[q4+13][r] = f2bf(b3.y);
    Bs[q4+14][r] = f2bf(b3.z); Bs[q4+15][r] = f2bf(b3.w);
    __syncthreads();
    #pragma unroll
    for (int kf = 0; kf < 2; ++kf) {
      short8 af[2], bfv[2];
      #pragma unroll
      for (int mt = 0; mt < 2; ++mt)
        af[mt] = *(const short8*)&As[wm*32 + mt*16 + l16][kf*32 + g*8];
      #pragma unroll
      for (int nt = 0; nt < 2; ++nt)
        bfv[nt] = *(const short8*)&Bs[wn*32 + nt*16 + l16][kf*32 + g*8];
      #pragma unroll
      for (int mt = 0; mt < 2; ++mt)
        #pragma unroll
        for (int nt = 0; nt < 2; ++nt)
          acc[mt][nt] = __builtin_amdgcn_mfma_f32_16x16x32_bf16(
              af[mt], bfv[nt], acc[mt][nt], 0, 0, 0);
    }
  }

  #pragma unroll
  for (int mt = 0; mt < 2; ++mt)
    #pragma unroll
    for (int nt = 0; nt < 2; ++nt)
      #pragma unroll
      for (int rg = 0; rg < 4; ++rg) {
        int row = bi*64 + wm*32 + mt*16 + g*4 + rg;
        int col = bj*64 + wn*32 + nt*16 + l16;
        float val = acc[mt][nt][rg] + bias[col];
        if (MODE == 0) {
          Cout[(size_t)row * Nn + col] = val;
        } else {
          int which = col >> 10, cc = col & 1023;
          int h = cc >> 6, d = cc & 63;
          int b = row >> 8, n = row & 255;
          size_t idx = (((size_t)(b*NH + h))*NQ + n)*HD + d;
          if (which == 0)      qbuf[idx] = f2bf(val * 0.180336878f); // 0.125*log2(e)
          else if (which == 1) knew[idx] = val;
          else                 vnew[idx] = val;
        }
      }
}

// ---------------------------------------------------------------------------
// Flash attention, split-KV, swapped-QK in-register softmax (exp2 domain).
// Grid: (B*H)*NSPLIT blocks, 512 threads = 8 waves x 32 queries.
// Double-buffered K/V LDS, 1 barrier per 64-key step.
// P lands directly in PV A-fragment layout via key permutation
//   sigma(g,j,kk) = 32kk + 16*(j>>2) + 4g + (j&3),
// matched on the B side by reading Vt[d][sigma] (transposed V in LDS).
// ---------------------------------------------------------------------------
__global__ __launch_bounds__(512, 4) void attn_k(
    const short* __restrict__ qbuf, const float* __restrict__ pastk,
    const float* __restrict__ pastv, const float* __restrict__ knew,
    const float* __restrict__ vnew, float* __restrict__ opart,
    float* __restrict__ mbuf, float* __restrict__ lbuf)
{
  __shared__ alignas(16) short Kt[2][64][72];   // [buf][key][d]
  __shared__ alignas(16) short Vt[2][64][70];   // [buf][d][key], 35-dword stride
  const int tid = threadIdx.x;
  const int lane = tid & 63, wave = tid >> 6;      // wave 0..7
  const int g = lane >> 4, l16 = lane & 15;
  const int s = blockIdx.x & (NSPLIT - 1), bh = blockIdx.x / NSPLIT;
  const int kr = tid >> 3, q8 = (tid & 7) << 3;    // K staging: 1 key x 8 d
  const int vp = tid >> 4, d4 = (tid & 15) << 2;   // V staging: keys 2vp,2vp+1 x 4 d

  // Q fragments (B-operand of S^T): lane holds Q[q=qt*16+l16][d=half*32+g*8..+7]
  short8 qf[2][2];
  #pragma unroll
  for (int qt = 0; qt < 2; ++qt)
    #pragma unroll
    for (int half = 0; half < 2; ++half)
      qf[qt][half] = *(const short8*)(qbuf +
          ((size_t)bh*NQ + wave*32 + qt*16 + l16)*HD + half*32 + g*8);

  f32x4 acc[2][4] = {};     // acc[qt][dt]: q = qt*16+g*4+rg, d = dt*16+l16
  float m_s[2], l_s[2];
  #pragma unroll
  for (int qt = 0; qt < 2; ++qt) { m_s[qt] = -INFINITY; l_s[qt] = 0.f; }

  const int first  = 8*s + (s < 4 ? s : 4);
  const int nsteps = 8 + (s < 4 ? 1 : 0);

  float4 ka[2], va, vc;
  auto load = [&](int step) {
    // step 0..127 -> past KV; 128..131 -> new KV (step-uniform branch)
    const float* kp = (step < 128)
        ? pastk + ((size_t)bh*LPAST + step*64 + kr)*HD + q8
        : knew  + ((size_t)bh*NQ + (step - 128)*64 + kr)*HD + q8;
    ka[0] = ((const float4*)kp)[0];
    ka[1] = ((const float4*)kp)[1];
    const float* vq = (step < 128)
        ? pastv + ((size_t)bh*LPAST + step*64 + 2*vp)*HD + d4
        : vnew  + ((size_t)bh*NQ + (step - 128)*64 + 2*vp)*HD + d4;
    va = *(const float4*)vq;
    vc = *(const float4*)(vq + HD);
  };
  auto stage = [&](int b) {
    const float* kf32 = (const float*)ka;
    int4v p = {cvtpk(kf32[0],kf32[1]), cvtpk(kf32[2],kf32[3]),
               cvtpk(kf32[4],kf32[5]), cvtpk(kf32[6],kf32[7])};
    *(int4v*)&Kt[b][kr][q8] = p;
    const float* af = (const float*)&va;
    const float* cf = (const float*)&vc;
    #pragma unroll
    for (int j = 0; j < 4; ++j)
      *(int*)&Vt[b][d4 + j][2*vp] = cvtpk(af[j], cf[j]);  // lo=key 2vp, hi=2vp+1
  };

  load(first);
  stage(0);
  if (nsteps > 1) load(first + 1);
  __syncthreads();

  for (int it = 0; it < nsteps; ++it) {
    const int cur = it & 1;

    short8 pa[2][2];
    #pragma unroll
    for (int qt = 0; qt < 2; ++qt) {
      f32x4 sv[4];
      #pragma unroll
      for (int kt = 0; kt < 4; ++kt) {
        // K fragment reloaded per qt to keep live range at 8 regs
        short8 k0 = *(const short8*)&Kt[cur][kt*16 + l16][g*8];
        short8 k1 = *(const short8*)&Kt[cur][kt*16 + l16][32 + g*8];
        f32x4 z = {0.f, 0.f, 0.f, 0.f};
        z = __builtin_amdgcn_mfma_f32_16x16x32_bf16(k0, qf[qt][0], z, 0,0,0);
        sv[kt] = __builtin_amdgcn_mfma_f32_16x16x32_bf16(k1, qf[qt][1], z, 0,0,0);
      }
      float mx = sv[0][0];
      #pragma unroll
      for (int kt = 0; kt < 4; ++kt)
        #pragma unroll
        for (int rg = 0; rg < 4; ++rg) mx = fmaxf(mx, sv[kt][rg]);
      mx = fmaxf(mx, __shfl_xor(mx, 16));
      mx = fmaxf(mx, __shfl_xor(mx, 32));
      float m_new = fmaxf(m_s[qt], mx);
      float al = exp2g(m_s[qt] - m_new);
      float ss = 0.f;
      #pragma unroll
      for (int kt = 0; kt < 4; ++kt)
        #pragma unroll
        for (int rg = 0; rg < 4; ++rg) {
          float p = exp2g(sv[kt][rg] - m_new);
          sv[kt][rg] = p; ss += p;
        }
      ss += __shfl_xor(ss, 16);
      ss += __shfl_xor(ss, 32);
      l_s[qt] = l_s[qt]*al + ss;
      m_s[qt] = m_new;
      #pragma unroll
      for (int rg = 0; rg < 4; ++rg) {
        float a = __shfl(al, g*4 + rg);
        #pragma unroll
        for (int dt = 0; dt < 4; ++dt) acc[qt][dt][rg] *= a;
      }
      int4v w0 = {cvtpk(sv[0][0],sv[0][1]), cvtpk(sv[0][2],sv[0][3]),
                  cvtpk(sv[1][0],sv[1][1]), cvtpk(sv[1][2],sv[1][3])};
      int4v w1 = {cvtpk(sv[2][0],sv[2][1]), cvtpk(sv[2][2],sv[2][3]),
                  cvtpk(sv[3][0],sv[3][1]), cvtpk(sv[3][2],sv[3][3])};
      pa[qt][0] = __builtin_bit_cast(short8, w0);
      pa[qt][1] = __builtin_bit_cast(short8, w1);
    }

    // PV: B-frag slot j <- Vt[d][32kk + 16*(j>>2) + 4g + (j&3)]
    #pragma unroll
    for (int kk = 0; kk < 2; ++kk) {
      #pragma unroll
      for (int dt = 0; dt < 4; ++dt) {
        const short* vrow = &Vt[cur][dt*16 + l16][kk*32 + 4*g];
        int i0 = *(const int*)(vrow);
        int i1 = *(const int*)(vrow + 2);
        int i2 = *(const int*)(vrow + 16);
        int i3 = *(const int*)(vrow + 18);
        int4v iv = {i0, i1, i2, i3};
        short8 vf = __builtin_bit_cast(short8, iv);
        #pragma unroll
        for (int qt = 0; qt < 2; ++qt)
          acc[qt][dt] = __builtin_amdgcn_mfma_f32_16x16x32_bf16(
              pa[qt][kk], vf, acc[qt][dt], 0,0,0);
      }
    }

    if (it + 1 < nsteps) {
      stage(1 - cur);                       // write NEXT step's tile (other buffer)
      if (it + 2 < nsteps) load(first + it + 2);
      __syncthreads();
    }
  }

  // Write partials
  size_t pbase = ((size_t)(bh * NSPLIT + s)) * NQ;
  #pragma unroll
  for (int qt = 0; qt < 2; ++qt)
    #pragma unroll
    for (int dt = 0; dt < 4; ++dt)
      #pragma unroll
      for (int rg = 0; rg < 4; ++rg) {
        int row = wave*32 + qt*16 + g*4 + rg;
        int col = dt*16 + l16;
        opart[(pbase + row)*HD + col] = acc[qt][dt][rg];
      }
  if (g == 0) {
    #pragma unroll
    for (int qt = 0; qt < 2; ++qt) {
      int q = wave*32 + qt*16 + l16;
      mbuf[pbase + q] = m_s[qt];
      lbuf[pbase + q] = l_s[qt];
    }
  }
}

// ---------------------------------------------------------------------------
// Combine NSPLIT partials per (b,h,n); write attn output [B,N,DIM] f32
// ---------------------------------------------------------------------------
__global__ __launch_bounds__(256) void combine_k(
    const float* __restrict__ opart, const float* __restrict__ mbuf,
    const float* __restrict__ lbuf, float* __restrict__ attnout)
{
  const int lane = threadIdx.x & 63, wave = threadIdx.x >> 6;
  const int rid = blockIdx.x * 4 + wave;   // 0 .. B*H*N-1
  const int bh = rid >> 8, n = rid & 255;
  const int b = bh >> 4, h = bh & 15;
  float M = -INFINITY;
  float ms[NSPLIT], ls[NSPLIT];
  #pragma unroll
  for (int s = 0; s < NSPLIT; ++s) {
    size_t base = ((size_t)(bh * NSPLIT + s)) * NQ + n;
    ms[s] = mbuf[base]; ls[s] = lbuf[base];
    M = fmaxf(M, ms[s]);
  }
  float denom = 0.f, o = 0.f;
  #pragma unroll
  for (int s = 0; s < NSPLIT; ++s) {
    float w = exp2g(ms[s] - M);
    denom += w * ls[s];
    o += w * opart[(((size_t)(bh * NSPLIT + s)) * NQ + n) * HD + lane];
  }
  attnout[((size_t)(b * NQ + n)) * DIMC + h * HD + lane] = o / denom;
}

// ---------------------------------------------------------------------------
extern "C" void kernel_launch(void* const* d_in, const int* in_sizes, int n_in,
                              void* d_out, int out_size, void* d_ws, size_t ws_size,
                              hipStream_t stream)
{
  const float* x     = (const float*)d_in[0];
  const float* pastk = (const float*)d_in[1];
  const float* pastv = (const float*)d_in[2];
  const float* wqkv  = (const float*)d_in[3];
  const float* bqkv  = (const float*)d_in[4];
  const float* wproj = (const float*)d_in[5];
  const float* bproj = (const float*)d_in[6];
  float* out = (float*)d_out;
  char* ws = (char*)d_ws;

  size_t off = 0;
  short* qbuf   = (short*)(ws + off); off += (size_t)BB*NH*NQ*HD*2;          // 1MB
  float* knew   = (float*)(ws + off); off += (size_t)BB*NH*NQ*HD*4;          // 2MB
  float* vnew   = (float*)(ws + off); off += (size_t)BB*NH*NQ*HD*4;          // 2MB
  float* opart  = (float*)(ws + off); off += (size_t)BB*NH*NSPLIT*NQ*HD*4;   // 32MB
  float* mbuf   = (float*)(ws + off); off += (size_t)BB*NH*NSPLIT*NQ*4;      // 512KB
  float* lbuf   = (float*)(ws + off); off += (size_t)BB*NH*NSPLIT*NQ*4;      // 512KB
  float* attnout= (float*)(ws + off); off += (size_t)BB*NQ*DIMC*4;           // 2MB

  // 1) QKV projection: [512,1024] x [1024,3072]
  gemm_k<1><<<(512/64)*(3072/64), 256, 0, stream>>>(
      x, wqkv, bqkv, nullptr, qbuf, knew, vnew, 512, 3072, 1024);
  // 2) split-KV flash attention
  attn_k<<<BB*NH*NSPLIT, 512, 0, stream>>>(
      qbuf, pastk, pastv, knew, vnew, opart, mbuf, lbuf);
  // 3) combine partials
  combine_k<<<BB*NH*NQ/4, 256, 0, stream>>>(opart, mbuf, lbuf, attnout);
  // 4) output projection: [512,1024] x [1024,1024]
  gemm_k<0><<<(512/64)*(1024/64), 256, 0, stream>>>(
      attnout, wproj, bproj, out, nullptr, nullptr, nullptr, 512, 1024, 1024);
}

// Round 6
// 91.818 us; speedup vs baseline: 3.6139x; 1.2361x over previous
//
#include <hip/hip_runtime.h>
#include <hip/hip_bf16.h>

// ---------------------------------------------------------------------------
// Fused attention: x@Wqkv -> q,k,v ; flash split-KV attention over
// concat(past_k, k_new) ; combine ; @Wproj -> out.
// B=2, N=256, DIM=1024, H=16, D=64, L=8192, total keys 8448 = 132 x 64.
// R6: R5's 8-wave/512-thread attn blocks (32 q/wave, acc[2][4]) but
// launch_bounds(512,2) -- NOT (512,4): forcing 128 total regs caused the
// compiler to split 64 arch + acc and spill ~50MB to scratch (R4/R5 lesson:
// WRITE_SIZE inflation is the spill fingerprint). Cap 256 -> no spill; let
// residency land where the natural allocation puts it (~10-13 waves/CU).
// ---------------------------------------------------------------------------

#define BB 2
#define NH 16
#define NQ 256
#define HD 64
#define DIMC 1024
#define LPAST 8192
#define TOTK 8448
#define NSPLIT 16
// 132 steps of 64 keys: splits 0..3 take 9 steps, 4..15 take 8.
// Steps 128..131 (inside split 15) read knew/vnew; selected per step.

typedef __attribute__((ext_vector_type(8))) short short8;
typedef __attribute__((ext_vector_type(4))) float f32x4;
typedef __attribute__((ext_vector_type(4))) int int4v;

#define DEVI static __device__ __forceinline__

DEVI float exp2g(float x) { return __builtin_amdgcn_exp2f(x); }  // v_exp_f32

DEVI int cvtpk(float lo, float hi) {     // dword = {bf16(lo), bf16(hi)}
  int r;
  asm("v_cvt_pk_bf16_f32 %0, %1, %2" : "=v"(r) : "v"(lo), "v"(hi));
  return r;
}
DEVI short f2bf(float f) {               // scalar f32 -> bf16 (RNE)
  union { float f; unsigned u; } v; v.f = f;
  unsigned r = v.u + 0x7FFFu + ((v.u >> 16) & 1u);
  return (short)(r >> 16);
}

// ---------------------------------------------------------------------------
// Generic 64x64-tile bf16 MFMA GEMM, f32 inputs converted during staging.
// MODE 0: Cout[row*Nn+col] = acc + bias[col]
// MODE 1: scatter into q (bf16, *0.125*log2e), k_new, v_new  [B,H,N,D]
// ---------------------------------------------------------------------------
template<int MODE>
__global__ __launch_bounds__(256, 2) void gemm_k(
    const float* __restrict__ A, const float* __restrict__ Bm,
    const float* __restrict__ bias, float* __restrict__ Cout,
    short* __restrict__ qbuf, float* __restrict__ knew, float* __restrict__ vnew,
    int M, int Nn, int K)
{
  __shared__ alignas(16) short As[64][72];   // [m][k] bf16, +8 pad
  __shared__ alignas(16) short Bs[64][72];   // [n][k] bf16 (B transposed)
  const int tid = threadIdx.x;
  const int lane = tid & 63, wave = tid >> 6;
  const int nblk = Nn >> 6;
  const int bi = blockIdx.x / nblk, bj = blockIdx.x % nblk;
  const int wm = wave >> 1, wn = wave & 1;
  const int g = lane >> 4, l16 = lane & 15;
  f32x4 acc[2][2] = {};
  const int r = tid >> 2, q4 = (tid & 3) << 4;

  for (int k0 = 0; k0 < K; k0 += 64) {
    const float* pa = A + (size_t)(bi * 64 + r) * K + (k0 + q4);
    float4 a0 = ((const float4*)pa)[0];
    float4 a1 = ((const float4*)pa)[1];
    float4 a2 = ((const float4*)pa)[2];
    float4 a3 = ((const float4*)pa)[3];
    const float* pb = Bm + (size_t)(k0 + r) * Nn + (bj * 64 + q4);
    float4 b0 = ((const float4*)pb)[0];
    float4 b1 = ((const float4*)pb)[1];
    float4 b2 = ((const float4*)pb)[2];
    float4 b3 = ((const float4*)pb)[3];
    __syncthreads();
    {
      int4v p0 = {cvtpk(a0.x,a0.y), cvtpk(a0.z,a0.w), cvtpk(a1.x,a1.y), cvtpk(a1.z,a1.w)};
      int4v p1 = {cvtpk(a2.x,a2.y), cvtpk(a2.z,a2.w), cvtpk(a3.x,a3.y), cvtpk(a3.z,a3.w)};
      *(int4v*)&As[r][q4]     = p0;
      *(int4v*)&As[r][q4 + 8] = p1;
    }
    Bs[q4+ 0][r] = f2bf(b0.x); Bs[q4+ 1][r] = f2bf(b0.y);
    Bs[q4+ 2][r] = f2bf(b0.z); Bs[q4+ 3][r] = f2bf(b0.w);
    Bs[q4+ 4][r] = f2bf(b1.x); Bs[q4+ 5][r] = f2bf(b1.y);
    Bs[q4+ 6][r] = f2bf(b1.z); Bs[q4+ 7][r] = f2bf(b1.w);
    Bs[q4+ 8][r] = f2bf(b2.x); Bs[q4+ 9][r] = f2bf(b2.y);
    Bs[q4+10][r] = f2bf(b2.z); Bs[q4+11][r] = f2bf(b2.w);
    Bs[q4+12][r] = f2bf(b3.x); Bs[q4+13][r] = f2bf(b3.y);
    Bs[q4+14][r] = f2bf(b3.z); Bs[q4+15][r] = f2bf(b3.w);
    __syncthreads();
    #pragma unroll
    for (int kf = 0; kf < 2; ++kf) {
      short8 af[2], bfv[2];
      #pragma unroll
      for (int mt = 0; mt < 2; ++mt)
        af[mt] = *(const short8*)&As[wm*32 + mt*16 + l16][kf*32 + g*8];
      #pragma unroll
      for (int nt = 0; nt < 2; ++nt)
        bfv[nt] = *(const short8*)&Bs[wn*32 + nt*16 + l16][kf*32 + g*8];
      #pragma unroll
      for (int mt = 0; mt < 2; ++mt)
        #pragma unroll
        for (int nt = 0; nt < 2; ++nt)
          acc[mt][nt] = __builtin_amdgcn_mfma_f32_16x16x32_bf16(
              af[mt], bfv[nt], acc[mt][nt], 0, 0, 0);
    }
  }

  #pragma unroll
  for (int mt = 0; mt < 2; ++mt)
    #pragma unroll
    for (int nt = 0; nt < 2; ++nt)
      #pragma unroll
      for (int rg = 0; rg < 4; ++rg) {
        int row = bi*64 + wm*32 + mt*16 + g*4 + rg;
        int col = bj*64 + wn*32 + nt*16 + l16;
        float val = acc[mt][nt][rg] + bias[col];
        if (MODE == 0) {
          Cout[(size_t)row * Nn + col] = val;
        } else {
          int which = col >> 10, cc = col & 1023;
          int h = cc >> 6, d = cc & 63;
          int b = row >> 8, n = row & 255;
          size_t idx = (((size_t)(b*NH + h))*NQ + n)*HD + d;
          if (which == 0)      qbuf[idx] = f2bf(val * 0.180336878f); // 0.125*log2(e)
          else if (which == 1) knew[idx] = val;
          else                 vnew[idx] = val;
        }
      }
}

// ---------------------------------------------------------------------------
// Flash attention, split-KV, swapped-QK in-register softmax (exp2 domain).
// Grid: (B*H)*NSPLIT blocks, 512 threads = 8 waves x 32 queries.
// Double-buffered K/V LDS, 1 barrier per 64-key step.
// P lands directly in PV A-fragment layout via key permutation
//   sigma(g,j,kk) = 32kk + 16*(j>>2) + 4g + (j&3),
// matched on the B side by reading Vt[d][sigma] (transposed V in LDS).
// ---------------------------------------------------------------------------
__global__ __launch_bounds__(512, 2) void attn_k(
    const short* __restrict__ qbuf, const float* __restrict__ pastk,
    const float* __restrict__ pastv, const float* __restrict__ knew,
    const float* __restrict__ vnew, float* __restrict__ opart,
    float* __restrict__ mbuf, float* __restrict__ lbuf)
{
  __shared__ alignas(16) short Kt[2][64][72];   // [buf][key][d]
  __shared__ alignas(16) short Vt[2][64][70];   // [buf][d][key], 35-dword stride
  const int tid = threadIdx.x;
  const int lane = tid & 63, wave = tid >> 6;      // wave 0..7
  const int g = lane >> 4, l16 = lane & 15;
  const int s = blockIdx.x & (NSPLIT - 1), bh = blockIdx.x / NSPLIT;
  const int kr = tid >> 3, q8 = (tid & 7) << 3;    // K staging: 1 key x 8 d
  const int vp = tid >> 4, d4 = (tid & 15) << 2;   // V staging: keys 2vp,2vp+1 x 4 d

  // Q fragments (B-operand of S^T): lane holds Q[q=qt*16+l16][d=half*32+g*8..+7]
  short8 qf[2][2];
  #pragma unroll
  for (int qt = 0; qt < 2; ++qt)
    #pragma unroll
    for (int half = 0; half < 2; ++half)
      qf[qt][half] = *(const short8*)(qbuf +
          ((size_t)bh*NQ + wave*32 + qt*16 + l16)*HD + half*32 + g*8);

  f32x4 acc[2][4] = {};     // acc[qt][dt]: q = qt*16+g*4+rg, d = dt*16+l16
  float m_s[2], l_s[2];
  #pragma unroll
  for (int qt = 0; qt < 2; ++qt) { m_s[qt] = -INFINITY; l_s[qt] = 0.f; }

  const int first  = 8*s + (s < 4 ? s : 4);
  const int nsteps = 8 + (s < 4 ? 1 : 0);

  float4 ka[2], va, vc;
  auto load = [&](int step) {
    // step 0..127 -> past KV; 128..131 -> new KV (step-uniform branch)
    const float* kp = (step < 128)
        ? pastk + ((size_t)bh*LPAST + step*64 + kr)*HD + q8
        : knew  + ((size_t)bh*NQ + (step - 128)*64 + kr)*HD + q8;
    ka[0] = ((const float4*)kp)[0];
    ka[1] = ((const float4*)kp)[1];
    const float* vq = (step < 128)
        ? pastv + ((size_t)bh*LPAST + step*64 + 2*vp)*HD + d4
        : vnew  + ((size_t)bh*NQ + (step - 128)*64 + 2*vp)*HD + d4;
    va = *(const float4*)vq;
    vc = *(const float4*)(vq + HD);
  };
  auto stage = [&](int b) {
    const float* kf32 = (const float*)ka;
    int4v p = {cvtpk(kf32[0],kf32[1]), cvtpk(kf32[2],kf32[3]),
               cvtpk(kf32[4],kf32[5]), cvtpk(kf32[6],kf32[7])};
    *(int4v*)&Kt[b][kr][q8] = p;
    const float* af = (const float*)&va;
    const float* cf = (const float*)&vc;
    #pragma unroll
    for (int j = 0; j < 4; ++j)
      *(int*)&Vt[b][d4 + j][2*vp] = cvtpk(af[j], cf[j]);  // lo=key 2vp, hi=2vp+1
  };

  load(first);
  stage(0);
  if (nsteps > 1) load(first + 1);
  __syncthreads();

  for (int it = 0; it < nsteps; ++it) {
    const int cur = it & 1;

    short8 pa[2][2];
    #pragma unroll
    for (int qt = 0; qt < 2; ++qt) {
      f32x4 sv[4];
      #pragma unroll
      for (int kt = 0; kt < 4; ++kt) {
        // K fragment reloaded per qt to keep live range at 8 regs
        short8 k0 = *(const short8*)&Kt[cur][kt*16 + l16][g*8];
        short8 k1 = *(const short8*)&Kt[cur][kt*16 + l16][32 + g*8];
        f32x4 z = {0.f, 0.f, 0.f, 0.f};
        z = __builtin_amdgcn_mfma_f32_16x16x32_bf16(k0, qf[qt][0], z, 0,0,0);
        sv[kt] = __builtin_amdgcn_mfma_f32_16x16x32_bf16(k1, qf[qt][1], z, 0,0,0);
      }
      float mx = sv[0][0];
      #pragma unroll
      for (int kt = 0; kt < 4; ++kt)
        #pragma unroll
        for (int rg = 0; rg < 4; ++rg) mx = fmaxf(mx, sv[kt][rg]);
      mx = fmaxf(mx, __shfl_xor(mx, 16));
      mx = fmaxf(mx, __shfl_xor(mx, 32));
      float m_new = fmaxf(m_s[qt], mx);
      float al = exp2g(m_s[qt] - m_new);
      float ss = 0.f;
      #pragma unroll
      for (int kt = 0; kt < 4; ++kt)
        #pragma unroll
        for (int rg = 0; rg < 4; ++rg) {
          float p = exp2g(sv[kt][rg] - m_new);
          sv[kt][rg] = p; ss += p;
        }
      ss += __shfl_xor(ss, 16);
      ss += __shfl_xor(ss, 32);
      l_s[qt] = l_s[qt]*al + ss;
      m_s[qt] = m_new;
      #pragma unroll
      for (int rg = 0; rg < 4; ++rg) {
        float a = __shfl(al, g*4 + rg);
        #pragma unroll
        for (int dt = 0; dt < 4; ++dt) acc[qt][dt][rg] *= a;
      }
      int4v w0 = {cvtpk(sv[0][0],sv[0][1]), cvtpk(sv[0][2],sv[0][3]),
                  cvtpk(sv[1][0],sv[1][1]), cvtpk(sv[1][2],sv[1][3])};
      int4v w1 = {cvtpk(sv[2][0],sv[2][1]), cvtpk(sv[2][2],sv[2][3]),
                  cvtpk(sv[3][0],sv[3][1]), cvtpk(sv[3][2],sv[3][3])};
      pa[qt][0] = __builtin_bit_cast(short8, w0);
      pa[qt][1] = __builtin_bit_cast(short8, w1);
    }

    // PV: B-frag slot j <- Vt[d][32kk + 16*(j>>2) + 4g + (j&3)]
    #pragma unroll
    for (int kk = 0; kk < 2; ++kk) {
      #pragma unroll
      for (int dt = 0; dt < 4; ++dt) {
        const short* vrow = &Vt[cur][dt*16 + l16][kk*32 + 4*g];
        int i0 = *(const int*)(vrow);
        int i1 = *(const int*)(vrow + 2);
        int i2 = *(const int*)(vrow + 16);
        int i3 = *(const int*)(vrow + 18);
        int4v iv = {i0, i1, i2, i3};
        short8 vf = __builtin_bit_cast(short8, iv);
        #pragma unroll
        for (int qt = 0; qt < 2; ++qt)
          acc[qt][dt] = __builtin_amdgcn_mfma_f32_16x16x32_bf16(
              pa[qt][kk], vf, acc[qt][dt], 0,0,0);
      }
    }

    if (it + 1 < nsteps) {
      stage(1 - cur);                       // write NEXT step's tile (other buffer)
      if (it + 2 < nsteps) load(first + it + 2);
      __syncthreads();
    }
  }

  // Write partials
  size_t pbase = ((size_t)(bh * NSPLIT + s)) * NQ;
  #pragma unroll
  for (int qt = 0; qt < 2; ++qt)
    #pragma unroll
    for (int dt = 0; dt < 4; ++dt)
      #pragma unroll
      for (int rg = 0; rg < 4; ++rg) {
        int row = wave*32 + qt*16 + g*4 + rg;
        int col = dt*16 + l16;
        opart[(pbase + row)*HD + col] = acc[qt][dt][rg];
      }
  if (g == 0) {
    #pragma unroll
    for (int qt = 0; qt < 2; ++qt) {
      int q = wave*32 + qt*16 + l16;
      mbuf[pbase + q] = m_s[qt];
      lbuf[pbase + q] = l_s[qt];
    }
  }
}

// ---------------------------------------------------------------------------
// Combine NSPLIT partials per (b,h,n); write attn output [B,N,DIM] f32
// ---------------------------------------------------------------------------
__global__ __launch_bounds__(256) void combine_k(
    const float* __restrict__ opart, const float* __restrict__ mbuf,
    const float* __restrict__ lbuf, float* __restrict__ attnout)
{
  const int lane = threadIdx.x & 63, wave = threadIdx.x >> 6;
  const int rid = blockIdx.x * 4 + wave;   // 0 .. B*H*N-1
  const int bh = rid >> 8, n = rid & 255;
  const int b = bh >> 4, h = bh & 15;
  float M = -INFINITY;
  float ms[NSPLIT], ls[NSPLIT];
  #pragma unroll
  for (int s = 0; s < NSPLIT; ++s) {
    size_t base = ((size_t)(bh * NSPLIT + s)) * NQ + n;
    ms[s] = mbuf[base]; ls[s] = lbuf[base];
    M = fmaxf(M, ms[s]);
  }
  float denom = 0.f, o = 0.f;
  #pragma unroll
  for (int s = 0; s < NSPLIT; ++s) {
    float w = exp2g(ms[s] - M);
    denom += w * ls[s];
    o += w * opart[(((size_t)(bh * NSPLIT + s)) * NQ + n) * HD + lane];
  }
  attnout[((size_t)(b * NQ + n)) * DIMC + h * HD + lane] = o / denom;
}

// ---------------------------------------------------------------------------
extern "C" void kernel_launch(void* const* d_in, const int* in_sizes, int n_in,
                              void* d_out, int out_size, void* d_ws, size_t ws_size,
                              hipStream_t stream)
{
  const float* x     = (const float*)d_in[0];
  const float* pastk = (const float*)d_in[1];
  const float* pastv = (const float*)d_in[2];
  const float* wqkv  = (const float*)d_in[3];
  const float* bqkv  = (const float*)d_in[4];
  const float* wproj = (const float*)d_in[5];
  const float* bproj = (const float*)d_in[6];
  float* out = (float*)d_out;
  char* ws = (char*)d_ws;

  size_t off = 0;
  short* qbuf   = (short*)(ws + off); off += (size_t)BB*NH*NQ*HD*2;          // 1MB
  float* knew   = (float*)(ws + off); off += (size_t)BB*NH*NQ*HD*4;          // 2MB
  float* vnew   = (float*)(ws + off); off += (size_t)BB*NH*NQ*HD*4;          // 2MB
  float* opart  = (float*)(ws + off); off += (size_t)BB*NH*NSPLIT*NQ*HD*4;   // 32MB
  float* mbuf   = (float*)(ws + off); off += (size_t)BB*NH*NSPLIT*NQ*4;      // 512KB
  float* lbuf   = (float*)(ws + off); off += (size_t)BB*NH*NSPLIT*NQ*4;      // 512KB
  float* attnout= (float*)(ws + off); off += (size_t)BB*NQ*DIMC*4;           // 2MB

  // 1) QKV projection: [512,1024] x [1024,3072]
  gemm_k<1><<<(512/64)*(3072/64), 256, 0, stream>>>(
      x, wqkv, bqkv, nullptr, qbuf, knew, vnew, 512, 3072, 1024);
  // 2) split-KV flash attention
  attn_k<<<BB*NH*NSPLIT, 512, 0, stream>>>(
      qbuf, pastk, pastv, knew, vnew, opart, mbuf, lbuf);
  // 3) combine partials
  combine_k<<<BB*NH*NQ/4, 256, 0, stream>>>(opart, mbuf, lbuf, attnout);
  // 4) output projection: [512,1024] x [1024,1024]
  gemm_k<0><<<(512/64)*(1024/64), 256, 0, stream>>>(
      attnout, wproj, bproj, out, nullptr, nullptr, nullptr, 512, 1024, 1024);
}